// Round 1
// baseline (1541.028 us; speedup 1.0000x reference)
//
#include <hip/hip_runtime.h>

// Problem constants (Network_29197187678952)
#define NN 50000          // nodes
#define NE 1600000        // edges
#define NB 8              // batch
#define NT 80             // timesteps
#define TN ((size_t)NT * NN)   // stride between batches in x/out: 4,000,000
#define DT_F 0.02f

// ---------------------------------------------------------------------------
// One-time setup kernels (rebuilt every call; deterministic up to atomic
// ordering inside a node's edge list, which only permutes an fp32 sum).
// ---------------------------------------------------------------------------

// v0 = bias (broadcast over batch, node-major (N,B) layout),
// alpha[n] = DT / max(tau, DT), cnt[n] = 0 (histogram scratch).
__global__ void init_nodes_kernel(const float* __restrict__ bias,
                                  const float* __restrict__ tc,
                                  float* __restrict__ v0,
                                  float* __restrict__ alpha,
                                  int* __restrict__ cnt) {
  int n = blockIdx.x * blockDim.x + threadIdx.x;
  if (n >= NN) return;
  float b = bias[n];
#pragma unroll
  for (int j = 0; j < NB; ++j) v0[(size_t)n * NB + j] = b;
  alpha[n] = DT_F / fmaxf(tc[n], DT_F);
  cnt[n] = 0;
}

__global__ void hist_kernel(const int* __restrict__ tgt, int* __restrict__ cnt) {
  int e = blockIdx.x * blockDim.x + threadIdx.x;
  if (e >= NE) return;
  atomicAdd(&cnt[tgt[e]], 1);
}

// Single-block exclusive scan over NN counts. In-place: cnt becomes the
// fill cursor (== row_ptr value); row_ptr gets the exclusive prefix + total.
__global__ void scan_kernel(int* __restrict__ cnt, int* __restrict__ row_ptr) {
  __shared__ int buf[2][1024];
  __shared__ int running_s;
  const int tid = threadIdx.x;
  if (tid == 0) running_s = 0;
  __syncthreads();
  for (int base = 0; base < NN; base += 1024) {
    int i = base + tid;
    int val = (i < NN) ? cnt[i] : 0;
    int sel = 0;
    buf[0][tid] = val;
    __syncthreads();
#pragma unroll
    for (int off = 1; off < 1024; off <<= 1) {
      int v = buf[sel][tid];
      if (tid >= off) v += buf[sel][tid - off];
      buf[sel ^ 1][tid] = v;
      sel ^= 1;
      __syncthreads();
    }
    int incl = buf[sel][tid];
    int run = running_s;
    if (i < NN) {
      int excl = run + incl - val;
      row_ptr[i] = excl;
      cnt[i] = excl;  // becomes fill cursor
    }
    __syncthreads();
    if (tid == 0) running_s = run + buf[sel][1023];
    __syncthreads();
  }
  if (tid == 0) row_ptr[NN] = running_s;
}

// Scatter edges into CSR-by-target order; fuse static edge weight.
__global__ void fill_kernel(const int* __restrict__ src, const int* __restrict__ tgt,
                            const float* __restrict__ sgn, const float* __restrict__ syn_cnt,
                            const float* __restrict__ syn_str,
                            int* __restrict__ cursor,
                            int* __restrict__ csr_src, float* __restrict__ csr_w) {
  int e = blockIdx.x * blockDim.x + threadIdx.x;
  if (e >= NE) return;
  int t = tgt[e];
  int pos = atomicAdd(&cursor[t], 1);
  csr_src[pos] = src[e];
  csr_w[pos] = sgn[e] * syn_cnt[e] * fmaxf(syn_str[e], 0.f);
}

// ---------------------------------------------------------------------------
// Per-timestep fused kernel: i_syn (CSR gather-reduce) + Euler update + store.
// 8 lanes per node; lane j accumulates all 8 batches over its edge subset,
// butterfly-reduce across the 8-lane group, lane j finalizes batch j.
// v state is node-major (N, 8): one edge gather = contiguous 32B.
// ---------------------------------------------------------------------------
__global__ __launch_bounds__(256) void step_kernel(
    const int* __restrict__ row_ptr,
    const int* __restrict__ csr_src,
    const float* __restrict__ csr_w,
    const float* __restrict__ v_old,
    float* __restrict__ v_new,
    const float* __restrict__ x_t,    // x + t*NN; batch stride TN
    const float* __restrict__ bias,
    const float* __restrict__ alpha,
    float* __restrict__ out_t) {      // out + t*NN; batch stride TN
  int gid = blockIdx.x * blockDim.x + threadIdx.x;
  int node = gid >> 3;
  int lane = gid & 7;
  if (node >= NN) return;

  int e0 = row_ptr[node];
  int e1 = row_ptr[node + 1];

  float acc[NB];
#pragma unroll
  for (int j = 0; j < NB; ++j) acc[j] = 0.f;

  for (int e = e0 + lane; e < e1; e += 8) {
    int s = csr_src[e];
    float w = csr_w[e];
    const float4* vp = (const float4*)(v_old + (size_t)s * NB);
    float4 va = vp[0];
    float4 vb = vp[1];
    acc[0] += w * fmaxf(va.x, 0.f);
    acc[1] += w * fmaxf(va.y, 0.f);
    acc[2] += w * fmaxf(va.z, 0.f);
    acc[3] += w * fmaxf(va.w, 0.f);
    acc[4] += w * fmaxf(vb.x, 0.f);
    acc[5] += w * fmaxf(vb.y, 0.f);
    acc[6] += w * fmaxf(vb.z, 0.f);
    acc[7] += w * fmaxf(vb.w, 0.f);
  }

  // reduce the 8 accumulators across the 8-lane group (groups are aligned
  // within the 64-lane wave, so xor-offsets < 8 stay inside the group)
#pragma unroll
  for (int off = 4; off > 0; off >>= 1) {
#pragma unroll
    for (int j = 0; j < NB; ++j) acc[j] += __shfl_xor(acc[j], off);
  }

  // lane j takes batch j — static-index cndmask chain (no scratch)
  float accsel = acc[0];
#pragma unroll
  for (int j = 1; j < NB; ++j) accsel = (lane == j) ? acc[j] : accsel;

  float a = alpha[node];
  float bs = bias[node];
  float v = v_old[(size_t)node * NB + lane];
  float xv = x_t[(size_t)lane * TN + node];
  float vn = v + a * (bs - v + accsel + xv);
  v_new[(size_t)node * NB + lane] = vn;
  out_t[(size_t)lane * TN + node] = vn;
}

// ---------------------------------------------------------------------------

extern "C" void kernel_launch(void* const* d_in, const int* in_sizes, int n_in,
                              void* d_out, int out_size, void* d_ws, size_t ws_size,
                              hipStream_t stream) {
  const float* x        = (const float*)d_in[0];
  const float* bias     = (const float*)d_in[1];
  const float* tc       = (const float*)d_in[2];
  const float* sgn      = (const float*)d_in[3];
  const float* syn_cnt  = (const float*)d_in[4];
  const float* syn_str  = (const float*)d_in[5];
  const int*   src      = (const int*)d_in[6];
  const int*   tgt      = (const int*)d_in[7];
  float* out = (float*)d_out;

  // Workspace carve-out (~16.6 MB)
  char* p = (char*)d_ws;
  auto take = [&p](size_t bytes) {
    char* r = p;
    p += (bytes + 255) & ~(size_t)255;
    return (void*)r;
  };
  float* v_a     = (float*)take((size_t)NN * NB * sizeof(float));
  float* v_b     = (float*)take((size_t)NN * NB * sizeof(float));
  float* alpha   = (float*)take((size_t)NN * sizeof(float));
  int*   row_ptr = (int*)take(((size_t)NN + 1) * sizeof(int));
  int*   cursor  = (int*)take((size_t)NN * sizeof(int));
  int*   csr_src = (int*)take((size_t)NE * sizeof(int));
  float* csr_w   = (float*)take((size_t)NE * sizeof(float));

  // Build CSR-by-target + node params (once per call)
  init_nodes_kernel<<<(NN + 255) / 256, 256, 0, stream>>>(bias, tc, v_a, alpha, cursor);
  hist_kernel<<<(NE + 255) / 256, 256, 0, stream>>>(tgt, cursor);
  scan_kernel<<<1, 1024, 0, stream>>>(cursor, row_ptr);
  fill_kernel<<<(NE + 255) / 256, 256, 0, stream>>>(src, tgt, sgn, syn_cnt, syn_str,
                                                    cursor, csr_src, csr_w);

  // Sequential Euler steps; v state ping-pongs in (N, B) layout
  const float* vin = v_a;
  float* vout = v_b;
  for (int t = 0; t < NT; ++t) {
    step_kernel<<<(NN * NB + 255) / 256, 256, 0, stream>>>(
        row_ptr, csr_src, csr_w, vin, vout,
        x + (size_t)t * NN, bias, alpha, out + (size_t)t * NN);
    float* tmp = (float*)vin;
    vin = vout;
    vout = tmp;
  }
}